// Round 5
// baseline (337.973 us; speedup 1.0000x reference)
//
#include <hip/hip_runtime.h>

// Problem constants (from reference): B=8192, M=16, DICT=64, N=8.
#define B_TOTAL 8192
#define M_DIM   16
#define DICT_N  64
#define N_DIM   8

// 1/k table for the Taylor recurrence v_k = (A v_{k-1}) / k (k is uniform).
__constant__ float c_invk[34] = {
    0.0f,
    1.0f,        1.0f/2.0f,  1.0f/3.0f,  1.0f/4.0f,
    1.0f/5.0f,   1.0f/6.0f,  1.0f/7.0f,  1.0f/8.0f,
    1.0f/9.0f,   1.0f/10.0f, 1.0f/11.0f, 1.0f/12.0f,
    1.0f/13.0f,  1.0f/14.0f, 1.0f/15.0f, 1.0f/16.0f,
    1.0f/17.0f,  1.0f/18.0f, 1.0f/19.0f, 1.0f/20.0f,
    1.0f/21.0f,  1.0f/22.0f, 1.0f/23.0f, 1.0f/24.0f,
    1.0f/25.0f,  1.0f/26.0f, 1.0f/27.0f, 1.0f/28.0f,
    1.0f/29.0f,  1.0f/30.0f, 1.0f/31.0f, 1.0f/32.0f, 1.0f/33.0f
};

// Thread-per-matrix (R2 structure — best arithmetic density), with two fixes:
//  1. psi comes from a 4KB LDS stage (one s per block) read with wave-uniform
//     addresses -> broadcast ds_read_b128. This removes R2's serialized
//     s_load_dwordx16 SMEM path and its SGPR pressure (SGPR_Count was 112).
//  2. amdgpu_waves_per_eu(5): 102-VGPR cap. Taylor live set is 88
//     (A[64]+v[8]+t[8]+o[8]; step 2 writes results back into v, no 4th
//     buffer) -> fits, 5 waves/SIMD instead of R2's 2.4 to hide FMA-chain
//     and LDS latency. R4's 8-lane split is abandoned (overhead-dominated).
__global__
__attribute__((amdgpu_flat_work_group_size(256, 256)))
__attribute__((amdgpu_waves_per_eu(5)))
void transop_expm_kernel(const float* __restrict__ x,
                         const float* __restrict__ c,
                         const float* __restrict__ psi,
                         float* __restrict__ out)
{
    __shared__ float psis[M_DIM * 64];   // psi[:, s, :, :] -> 16 x 64 floats

    const int tid = threadIdx.x;
    const int s   = blockIdx.x & (DICT_N - 1);          // one s per block
    const int b   = (blockIdx.x >> 6) * 256 + tid;      // per-lane batch

    // ---- Stage psi[:, s] into LDS: 1024 floats, one float4 per thread ----
    {
        const int m  = tid >> 4;          // 0..15
        const int f4 = tid & 15;          // float4 index within 64 floats
        const float4 pv = *reinterpret_cast<const float4*>(
            psi + (size_t)m * (DICT_N * 64) + (size_t)s * 64 + f4 * 4);
        *reinterpret_cast<float4*>(&psis[m * 64 + f4 * 4]) = pv;
    }
    __syncthreads();

    // ---- Build A[n,k] = sum_m c[b,m] * psi[m, s, n, k] ----
    float A[64];
#pragma unroll
    for (int i = 0; i < 64; ++i) A[i] = 0.0f;

    const float4* cb4 = reinterpret_cast<const float4*>(c + (size_t)b * M_DIM);
#pragma unroll
    for (int mq = 0; mq < 4; ++mq) {
        const float4 cv = cb4[mq];                       // c[b, 4mq..+4)
        const float cmv[4] = { cv.x, cv.y, cv.z, cv.w };
#pragma unroll
        for (int mm = 0; mm < 4; ++mm) {
            const float cm = cmv[mm];                    // const idx (unroll)
            const float* pm = &psis[(mq * 4 + mm) * 64]; // uniform LDS addr
#pragma unroll
            for (int i = 0; i < 64; ++i)
                A[i] = fmaf(cm, pm[i], A[i]);            // broadcast ds_read
        }
    }

    // ---- Load x block: v = x[b, s*8 .. +8) ----
    const float* xb = x + (size_t)b * (DICT_N * N_DIM) + (size_t)s * N_DIM;
    float v[8], o[8];
    {
        const float4 t0 = reinterpret_cast<const float4*>(xb)[0];
        const float4 t1 = reinterpret_cast<const float4*>(xb)[1];
        v[0] = t0.x; v[1] = t0.y; v[2] = t0.z; v[3] = t0.w;
        v[4] = t1.x; v[5] = t1.y; v[6] = t1.z; v[7] = t1.w;
    }
#pragma unroll
    for (int i = 0; i < 8; ++i) o[i] = v[i];             // k=0 term

    // ---- Taylor: o = sum_k A^k x / k!, 2 steps/trip, j-outer (ILP=8) ----
#pragma unroll 1
    for (int k = 1; k <= 31; k += 2) {
        const float inva = c_invk[k];
        const float invb = c_invk[k + 1];

        float t[8];
#pragma unroll
        for (int i = 0; i < 8; ++i) t[i] = A[i * 8] * v[0];
#pragma unroll
        for (int j = 1; j < 8; ++j)
#pragma unroll
            for (int i = 0; i < 8; ++i)
                t[i] = fmaf(A[i * 8 + j], v[j], t[i]);
#pragma unroll
        for (int i = 0; i < 8; ++i) { t[i] *= inva; o[i] += t[i]; }

        // Step 2 consumes t only; old v is dead -> write results into v.
#pragma unroll
        for (int i = 0; i < 8; ++i) v[i] = A[i * 8] * t[0];
#pragma unroll
        for (int j = 1; j < 8; ++j)
#pragma unroll
            for (int i = 0; i < 8; ++i)
                v[i] = fmaf(A[i * 8 + j], t[j], v[i]);

        float mx = 0.0f;
#pragma unroll
        for (int i = 0; i < 8; ++i) {
            v[i] *= invb;
            o[i] += v[i];
            mx = fmaxf(mx, fabsf(v[i]));
        }
        // Tail after all-lanes mx<2e-4 adds <=1e-3 abs error vs the 1.56
        // threshold (R2/R4 margin: 0.0625).
        if (__all(mx < 2e-4f)) break;
    }

    // ---- Store out[b, s*8 .. +8) ----
    float* ob = out + (size_t)b * (DICT_N * N_DIM) + (size_t)s * N_DIM;
    float4 r0, r1;
    r0.x = o[0]; r0.y = o[1]; r0.z = o[2]; r0.w = o[3];
    r1.x = o[4]; r1.y = o[5]; r1.z = o[6]; r1.w = o[7];
    reinterpret_cast<float4*>(ob)[0] = r0;
    reinterpret_cast<float4*>(ob)[1] = r1;
}

extern "C" void kernel_launch(void* const* d_in, const int* in_sizes, int n_in,
                              void* d_out, int out_size, void* d_ws, size_t ws_size,
                              hipStream_t stream)
{
    const float* x   = (const float*)d_in[0];  // (8192, 512)
    const float* c   = (const float*)d_in[1];  // (8192, 16)
    const float* psi = (const float*)d_in[2];  // (16, 64, 8, 8)
    float* out = (float*)d_out;                // (8192, 512)

    // s fast-varying: consecutive blocks share the same 256-b range ->
    // adjacent x/out columns, good line utilization. 64 s * 32 bg = 2048.
    dim3 grid(DICT_N * (B_TOTAL / 256));
    dim3 block(256);
    hipLaunchKernelGGL(transop_expm_kernel, grid, block, 0, stream,
                       x, c, psi, out);
}

// Round 8
// 143.010 us; speedup vs baseline: 2.3633x; 2.3633x over previous
//
#include <hip/hip_runtime.h>

// Problem constants (from reference): B=8192, M=16, DICT=64, N=8.
#define B_TOTAL 8192
#define M_DIM   16
#define DICT_N  64
#define N_DIM   8

// 1/k table for the Taylor recurrence v_k = (A v_{k-1}) / k (k is uniform).
__constant__ float c_invk[34] = {
    0.0f,
    1.0f,        1.0f/2.0f,  1.0f/3.0f,  1.0f/4.0f,
    1.0f/5.0f,   1.0f/6.0f,  1.0f/7.0f,  1.0f/8.0f,
    1.0f/9.0f,   1.0f/10.0f, 1.0f/11.0f, 1.0f/12.0f,
    1.0f/13.0f,  1.0f/14.0f, 1.0f/15.0f, 1.0f/16.0f,
    1.0f/17.0f,  1.0f/18.0f, 1.0f/19.0f, 1.0f/20.0f,
    1.0f/21.0f,  1.0f/22.0f, 1.0f/23.0f, 1.0f/24.0f,
    1.0f/25.0f,  1.0f/26.0f, 1.0f/27.0f, 1.0f/28.0f,
    1.0f/29.0f,  1.0f/30.0f, 1.0f/31.0f, 1.0f/32.0f, 1.0f/33.0f
};

// Thread-per-matrix (R2 structure — best arithmetic density; issue-active
// time already ~= the 17us VALU floor). Single fix vs R2: psi comes from a
// 4KB LDS stage (one s per block) read with wave-uniform broadcast
// ds_read_b128 instead of R2's serialized s_load_dwordx16 SMEM chains
// (R2: SGPR_Count=112, 73% stall during A-build).
//
// NO occupancy/register hints: R2/R5 showed the default allocator parks
// A[64] in AGPRs (VALU reads AGPRs directly on gfx90a+) with ZERO scratch,
// while every forced cap (launch_bounds(256,4), waves_per_eu(5)) either
// was ignored or caused catastrophic scratch spill (R5: 839MB writes).
__global__ __launch_bounds__(256)
void transop_expm_kernel(const float* __restrict__ x,
                         const float* __restrict__ c,
                         const float* __restrict__ psi,
                         float* __restrict__ out)
{
    __shared__ float psis[M_DIM * 64];   // psi[:, s, :, :] -> 16 x 64 floats

    const int tid = threadIdx.x;
    const int s   = blockIdx.x & (DICT_N - 1);          // one s per block
    const int b   = (blockIdx.x >> 6) * 256 + tid;      // per-lane batch

    // ---- Stage psi[:, s] into LDS: 1024 floats, one float4 per thread ----
    {
        const int m  = tid >> 4;          // 0..15
        const int f4 = tid & 15;          // float4 index within 64 floats
        const float4 pv = *reinterpret_cast<const float4*>(
            psi + (size_t)m * (DICT_N * 64) + (size_t)s * 64 + f4 * 4);
        *reinterpret_cast<float4*>(&psis[m * 64 + f4 * 4]) = pv;
    }
    __syncthreads();

    // ---- Build A[n,k] = sum_m c[b,m] * psi[m, s, n, k] ----
    float A[64];
#pragma unroll
    for (int i = 0; i < 64; ++i) A[i] = 0.0f;

    const float4* cb4 = reinterpret_cast<const float4*>(c + (size_t)b * M_DIM);
#pragma unroll
    for (int mq = 0; mq < 4; ++mq) {
        const float4 cv = cb4[mq];                       // c[b, 4mq..+4)
        const float cmv[4] = { cv.x, cv.y, cv.z, cv.w };
#pragma unroll
        for (int mm = 0; mm < 4; ++mm) {
            const float cm = cmv[mm];                    // const idx (unroll)
            const float* pm = &psis[(mq * 4 + mm) * 64]; // uniform LDS addr
#pragma unroll
            for (int i = 0; i < 64; ++i)
                A[i] = fmaf(cm, pm[i], A[i]);            // broadcast ds_read
        }
    }

    // ---- Load x block: v = x[b, s*8 .. +8) ----
    const float* xb = x + (size_t)b * (DICT_N * N_DIM) + (size_t)s * N_DIM;
    float v[8], o[8];
    {
        const float4 t0 = reinterpret_cast<const float4*>(xb)[0];
        const float4 t1 = reinterpret_cast<const float4*>(xb)[1];
        v[0] = t0.x; v[1] = t0.y; v[2] = t0.z; v[3] = t0.w;
        v[4] = t1.x; v[5] = t1.y; v[6] = t1.z; v[7] = t1.w;
    }
#pragma unroll
    for (int i = 0; i < 8; ++i) o[i] = v[i];             // k=0 term

    // ---- Taylor: o = sum_k A^k x / k!, 2 steps/trip, j-outer (ILP=8) ----
#pragma unroll 1
    for (int k = 1; k <= 31; k += 2) {
        const float inva = c_invk[k];
        const float invb = c_invk[k + 1];

        float t[8];
#pragma unroll
        for (int i = 0; i < 8; ++i) t[i] = A[i * 8] * v[0];
#pragma unroll
        for (int j = 1; j < 8; ++j)
#pragma unroll
            for (int i = 0; i < 8; ++i)
                t[i] = fmaf(A[i * 8 + j], v[j], t[i]);
#pragma unroll
        for (int i = 0; i < 8; ++i) { t[i] *= inva; o[i] += t[i]; }

        // Step 2 consumes t only; old v is dead -> write results into v.
#pragma unroll
        for (int i = 0; i < 8; ++i) v[i] = A[i * 8] * t[0];
#pragma unroll
        for (int j = 1; j < 8; ++j)
#pragma unroll
            for (int i = 0; i < 8; ++i)
                v[i] = fmaf(A[i * 8 + j], t[j], v[i]);

        float mx = 0.0f;
#pragma unroll
        for (int i = 0; i < 8; ++i) {
            v[i] *= invb;
            o[i] += v[i];
            mx = fmaxf(mx, fabsf(v[i]));
        }
        // Tail after all-lanes mx<2e-4 adds <=1e-3 abs error vs the 1.56
        // threshold (R2/R4 margin: 0.0625).
        if (__all(mx < 2e-4f)) break;
    }

    // ---- Store out[b, s*8 .. +8) ----
    float* ob = out + (size_t)b * (DICT_N * N_DIM) + (size_t)s * N_DIM;
    float4 r0, r1;
    r0.x = o[0]; r0.y = o[1]; r0.z = o[2]; r0.w = o[3];
    r1.x = o[4]; r1.y = o[5]; r1.z = o[6]; r1.w = o[7];
    reinterpret_cast<float4*>(ob)[0] = r0;
    reinterpret_cast<float4*>(ob)[1] = r1;
}

extern "C" void kernel_launch(void* const* d_in, const int* in_sizes, int n_in,
                              void* d_out, int out_size, void* d_ws, size_t ws_size,
                              hipStream_t stream)
{
    const float* x   = (const float*)d_in[0];  // (8192, 512)
    const float* c   = (const float*)d_in[1];  // (8192, 16)
    const float* psi = (const float*)d_in[2];  // (16, 64, 8, 8)
    float* out = (float*)d_out;                // (8192, 512)

    // s fast-varying: consecutive blocks share the same 256-b range ->
    // adjacent 32B x/out column spans hit the same 128B lines via L2.
    dim3 grid(DICT_N * (B_TOTAL / 256));
    dim3 block(256);
    hipLaunchKernelGGL(transop_expm_kernel, grid, block, 0, stream,
                       x, c, psi, out);
}

// Round 9
// 136.513 us; speedup vs baseline: 2.4758x; 1.0476x over previous
//
#include <hip/hip_runtime.h>

// Problem constants (from reference): B=8192, M=16, DICT=64, N=8.
#define B_TOTAL 8192
#define M_DIM   16
#define DICT_N  64
#define N_DIM   8

// 1/k table for the Taylor recurrence v_k = (A v_{k-1}) / k (k is uniform).
__constant__ float c_invk[34] = {
    0.0f,
    1.0f,        1.0f/2.0f,  1.0f/3.0f,  1.0f/4.0f,
    1.0f/5.0f,   1.0f/6.0f,  1.0f/7.0f,  1.0f/8.0f,
    1.0f/9.0f,   1.0f/10.0f, 1.0f/11.0f, 1.0f/12.0f,
    1.0f/13.0f,  1.0f/14.0f, 1.0f/15.0f, 1.0f/16.0f,
    1.0f/17.0f,  1.0f/18.0f, 1.0f/19.0f, 1.0f/20.0f,
    1.0f/21.0f,  1.0f/22.0f, 1.0f/23.0f, 1.0f/24.0f,
    1.0f/25.0f,  1.0f/26.0f, 1.0f/27.0f, 1.0f/28.0f,
    1.0f/29.0f,  1.0f/30.0f, 1.0f/31.0f, 1.0f/32.0f, 1.0f/33.0f
};

// Swap values between lane pairs (lane ^ 1) via DPP quad_perm [1,0,3,2].
// Pure VALU op — no LDS pipe, no latency beyond a VALU dep.
__device__ __forceinline__ float dpp_swap1(float v) {
    return __int_as_float(
        __builtin_amdgcn_mov_dpp(__float_as_int(v), 0xB1, 0xF, 0xF, true));
}

// TWO threads per (b,s) matrix, split by row halves (lane&1: rows 0-3 / 4-7).
// Why: thread-per-matrix needs A[64] -> ~150 unified regs -> 2.4 waves/SIMD
// (R2, latency-bound); LDS-staged psi saturates the per-CU LDS pipe with
// broadcast wave-ops (R8: ~41us of ds_read_b128 issue). Here each thread
// holds 32 A values (~75 VGPR -> ~6 waves/SIMD), psi operands come as
// per-lane global b128 loads (2 distinct addrs/wave-op, L1/L2-resident
// 256KB -> coalescer broadcast), and the Taylor half-vector exchange is
// 4x dpp quad_perm (VALU) per step. No LDS usage at all.
//
// Per-thread A column order = [own-half cols, partner-half cols], realized
// by a per-lane +-16B offset at build time:
//   even (p=0), rows 0-3:  Ao = cols 0-3, Ap = cols 4-7
//   odd  (p=1), rows 4-7:  Ao = cols 4-7, Ap = cols 0-3
// Then every step, for both parities: t = Ao . v_own + Ap . v_partner,
// v_own = t, v_partner = dpp_swap1(t). No cndmask, no divergence.
__global__ __launch_bounds__(256)
void transop_expm_kernel(const float* __restrict__ x,
                         const float* __restrict__ c,
                         const float* __restrict__ psi,
                         float* __restrict__ out)
{
    const int tid = threadIdx.x;
    const int p   = tid & 1;                         // row-half parity
    const int s   = blockIdx.x & (DICT_N - 1);       // block-uniform
    const int b   = (blockIdx.x >> 6) * 128 + (tid >> 1);

    const int jown = p * 4;                          // own-cols float offset
    const int jpar = 4 - jown;                       // partner-cols offset

    // psi[m, s, row, col] flat = m*4096 + s*64 + row*8 + col.
    // This thread's rows start at p*4.
    const float* pbase = psi + (size_t)s * 64 + (size_t)(p * 4) * 8;

    // ---- Build A halves: Ao[i][q], Ap[i][q] for own rows i=0..3 ----
    float Ao[16], Ap[16];
#pragma unroll
    for (int i = 0; i < 16; ++i) { Ao[i] = 0.0f; Ap[i] = 0.0f; }

    const float4* cb4 = reinterpret_cast<const float4*>(c + (size_t)b * M_DIM);
#pragma unroll 1
    for (int mq = 0; mq < 4; ++mq) {
        const float4 cv = cb4[mq];                   // c[b, 4mq..+4)
        const float cmv[4] = { cv.x, cv.y, cv.z, cv.w };
#pragma unroll
        for (int mm = 0; mm < 4; ++mm) {
            const float cm = cmv[mm];                // static idx after unroll
            const float* pm = pbase + (size_t)(mq * 4 + mm) * (DICT_N * 64);
#pragma unroll
            for (int i = 0; i < 4; ++i) {
                const float4 po = *reinterpret_cast<const float4*>(pm + i * 8 + jown);
                const float4 pq = *reinterpret_cast<const float4*>(pm + i * 8 + jpar);
                Ao[i * 4 + 0] = fmaf(cm, po.x, Ao[i * 4 + 0]);
                Ao[i * 4 + 1] = fmaf(cm, po.y, Ao[i * 4 + 1]);
                Ao[i * 4 + 2] = fmaf(cm, po.z, Ao[i * 4 + 2]);
                Ao[i * 4 + 3] = fmaf(cm, po.w, Ao[i * 4 + 3]);
                Ap[i * 4 + 0] = fmaf(cm, pq.x, Ap[i * 4 + 0]);
                Ap[i * 4 + 1] = fmaf(cm, pq.y, Ap[i * 4 + 1]);
                Ap[i * 4 + 2] = fmaf(cm, pq.z, Ap[i * 4 + 2]);
                Ap[i * 4 + 3] = fmaf(cm, pq.w, Ap[i * 4 + 3]);
            }
        }
    }

    // ---- v halves: vo = own half of x-block, vp = partner half (dpp) ----
    const float* xb = x + (size_t)b * (DICT_N * N_DIM) + s * N_DIM + jown;
    const float4 xv = *reinterpret_cast<const float4*>(xb);
    float vo[4] = { xv.x, xv.y, xv.z, xv.w };
    float vp[4];
#pragma unroll
    for (int i = 0; i < 4; ++i) vp[i] = dpp_swap1(vo[i]);
    float o[4] = { vo[0], vo[1], vo[2], vo[3] };     // k=0 term (own rows)

    // ---- Taylor: o += (A^k x / k!)[own rows], 2 steps per trip ----
#pragma unroll 1
    for (int k = 1; k <= 31; k += 2) {
        const float inva = c_invk[k];
        const float invb = c_invk[k + 1];

        // step 1: t = Ao.vo + Ap.vp (q-outer, 4 parallel row chains)
        float t[4];
#pragma unroll
        for (int i = 0; i < 4; ++i) t[i] = Ao[i * 4] * vo[0];
#pragma unroll
        for (int q = 1; q < 4; ++q)
#pragma unroll
            for (int i = 0; i < 4; ++i)
                t[i] = fmaf(Ao[i * 4 + q], vo[q], t[i]);
#pragma unroll
        for (int q = 0; q < 4; ++q)
#pragma unroll
            for (int i = 0; i < 4; ++i)
                t[i] = fmaf(Ap[i * 4 + q], vp[q], t[i]);
#pragma unroll
        for (int i = 0; i < 4; ++i) { t[i] *= inva; o[i] += t[i]; }
        float tp[4];
#pragma unroll
        for (int i = 0; i < 4; ++i) tp[i] = dpp_swap1(t[i]);

        // step 2: u = Ao.t + Ap.tp
        float u[4];
#pragma unroll
        for (int i = 0; i < 4; ++i) u[i] = Ao[i * 4] * t[0];
#pragma unroll
        for (int q = 1; q < 4; ++q)
#pragma unroll
            for (int i = 0; i < 4; ++i)
                u[i] = fmaf(Ao[i * 4 + q], t[q], u[i]);
#pragma unroll
        for (int q = 0; q < 4; ++q)
#pragma unroll
            for (int i = 0; i < 4; ++i)
                u[i] = fmaf(Ap[i * 4 + q], tp[q], u[i]);

        float mx = 0.0f;
#pragma unroll
        for (int i = 0; i < 4; ++i) {
            u[i] *= invb;
            o[i] += u[i];
            mx = fmaxf(mx, fabsf(u[i]));
        }
        // Wave-uniform exit: all lanes (= all 32 matrices, both halves)
        // below 2e-4 -> remaining tail adds <=1e-3 abs error vs the 1.56
        // threshold (R2/R8 margin: 0.0625). Break BEFORE the dpp exchange.
        if (__all(mx < 2e-4f)) break;

#pragma unroll
        for (int i = 0; i < 4; ++i) {
            vo[i] = u[i];
            vp[i] = dpp_swap1(u[i]);
        }
    }

    // ---- Store own half: out[b, s*8 + jown .. +4) ----
    float* ob = out + (size_t)b * (DICT_N * N_DIM) + s * N_DIM + jown;
    float4 r;
    r.x = o[0]; r.y = o[1]; r.z = o[2]; r.w = o[3];
    *reinterpret_cast<float4*>(ob) = r;
}

extern "C" void kernel_launch(void* const* d_in, const int* in_sizes, int n_in,
                              void* d_out, int out_size, void* d_ws, size_t ws_size,
                              hipStream_t stream)
{
    const float* x   = (const float*)d_in[0];  // (8192, 512)
    const float* c   = (const float*)d_in[1];  // (8192, 16)
    const float* psi = (const float*)d_in[2];  // (16, 64, 8, 8)
    float* out = (float*)d_out;                // (8192, 512)

    // 2 threads per matrix: 256-thread block = 128 matrices (one s).
    // s fast-varying across blocks for x/out L2 line sharing.
    // 64 s * (8192/128) = 4096 blocks.
    dim3 grid(DICT_N * (B_TOTAL / 128));
    dim3 block(256);
    hipLaunchKernelGGL(transop_expm_kernel, grid, block, 0, stream,
                       x, c, psi, out);
}